// Round 7
// baseline (155.266 us; speedup 1.0000x reference)
//
#include <hip/hip_runtime.h>
#include <cstdint>
#include <cstddef>

namespace {
constexpr int kN    = 65536;     // nodes
constexpr int kF    = 256;       // feats
constexpr int kC    = 64;        // pools per graph
constexpr int kNPG  = 1024;      // nodes per graph
constexpr int kB    = 64;        // graphs
constexpr int kE    = 2097152;   // edges
constexpr int kK    = kB * kC;   // 4096 global clusters

// d_out offsets (in floats)
constexpr size_t OFF_OUT  = 0;                           // [4096,256]
constexpr size_t OFF_EIDX = (size_t)kK * kF;             // 1048576  [2,262144]
constexpr size_t OFF_ADJ  = OFF_EIDX + 2ull*kB*kC*kC;    // 1572864  [262144]
constexpr size_t OFF_LL   = OFF_ADJ + (size_t)kB*kC*kC;  // 1835008
constexpr size_t OFF_Z    = OFF_LL + 1;                  // 1835009
constexpr size_t OFF_BOUT = OFF_Z + 1;                   // 1835010  [4096]
constexpr size_t OFF_BPTR = OFF_BOUT + kK;               // 1839106  [65]

// ws offsets (bytes). PERM/START overlap PADJ (stream-disjoint lifetimes).
constexpr size_t WS_C    = 0;        // int[65536]
constexpr size_t WS_V    = 262144;   // float[65536]
constexpr size_t WS_VS2  = 524288;   // float[4096]
constexpr size_t WS_A2   = 540672;   // float[256]
constexpr size_t WS_PERM = 544768;   // int[65536]   (dead after k_pool_x)
constexpr size_t WS_STRT = 806912;   // int[64*65]   (dead after k_pool_x)
constexpr size_t WS_PADJ = 544768;   // float[256*4096] = 4 MiB (k_adj onward)
} // namespace

// ---------------------------------------------------------------- constants
__global__ __launch_bounds__(256) void k_const(float* __restrict__ out)
{
    const int i = blockIdx.x * 256 + threadIdx.x;
    constexpr int E2 = 2 * kB * kC * kC;      // 524288
    if (i < E2) {
        const int half = i >= kB*kC*kC;
        const int idx  = half ? i - kB*kC*kC : i;
        const int bb = idx >> 12, rem = idx & 4095;
        const int val = half ? bb*kC + (rem & 63) : bb*kC + (rem >> 6);
        out[OFF_EIDX + i] = (float)val;
    } else if (i < E2 + kK) {
        const int j = i - E2;
        out[OFF_BOUT + j] = (float)(j >> 6);
    } else if (i < E2 + kK + kB + 1) {
        const int j = i - (E2 + kK);
        out[OFF_BPTR + j] = (float)(j * kC);
    }
}

// ------------------------------------------------- K1: logits -> c, v
// GEMM M=65536 N=64 K=256. 1024 single-wave blocks (1 wave/SIMD, all 4 SIMDs
// busy), BM=64, 8x8 reg tile. NO __syncthreads (single wave). x double-
// buffered in LDS ([k][node], stride 68: transpose-writes conflict-free via
// node=tid, frag reads 2-way=free). W read DIRECT from global per kk
// (8 KB/chunk, L1-resident) so the LDS pipe serves only x-frags:
// per kk-round/CU 96 LDS-cyc < 128 FMA SIMD-cyc -> compute-bound.
// T14: chunk c+1 global loads issued before compute of chunk c.
__global__ __launch_bounds__(64) void k_logits(
    const float* __restrict__ x, const float* __restrict__ Wm,
    const float* __restrict__ bv, int* __restrict__ carr,
    float* __restrict__ varr)
{
    constexpr int KC = 32, STR = 68;
    __shared__ float xs[2][KC * STR];    // 17408 B
    const int tid = threadIdx.x;         // 0..63
    const int tx  = tid & 7;             // col group: cols tx*8 .. +7
    const int ty  = tid >> 3;            // node group: nodes ty*8 .. +7
    const int nbase = blockIdx.x * 64;
    const float* __restrict__ xrow = x + (size_t)(nbase + tid) * kF;

    float acc[8][8];
    {
        const float4 b0 = *reinterpret_cast<const float4*>(bv + tx*8);
        const float4 b1 = *reinterpret_cast<const float4*>(bv + tx*8 + 4);
        const float bb[8] = {b0.x,b0.y,b0.z,b0.w, b1.x,b1.y,b1.z,b1.w};
#pragma unroll
        for (int i = 0; i < 8; ++i)
#pragma unroll
            for (int j = 0; j < 8; ++j) acc[i][j] = bb[j];
    }

    float4 gx[8];
    // prologue: load + stage chunk 0 (this thread owns row nbase+tid)
#pragma unroll
    for (int r = 0; r < 8; ++r)
        gx[r] = *reinterpret_cast<const float4*>(xrow + r*4);
#pragma unroll
    for (int r = 0; r < 8; ++r) {
        xs[0][(r*4+0)*STR + tid] = gx[r].x;
        xs[0][(r*4+1)*STR + tid] = gx[r].y;
        xs[0][(r*4+2)*STR + tid] = gx[r].z;
        xs[0][(r*4+3)*STR + tid] = gx[r].w;
    }

#pragma unroll 2
    for (int c = 0; c < 8; ++c) {
        const int cur = c & 1;
        if (c < 7) {
#pragma unroll
            for (int r = 0; r < 8; ++r)
                gx[r] = *reinterpret_cast<const float4*>(
                    xrow + (c+1)*KC + r*4);
        }
        const float* __restrict__ wbase = Wm + (size_t)c*KC*kC + tx*8;
#pragma unroll 4
        for (int kk = 0; kk < KC; ++kk) {
            const float4 xa = *reinterpret_cast<const float4*>(
                &xs[cur][kk*STR + ty*8]);
            const float4 xb = *reinterpret_cast<const float4*>(
                &xs[cur][kk*STR + ty*8 + 4]);
            const float4 w0 = *reinterpret_cast<const float4*>(
                wbase + (size_t)kk*kC);
            const float4 w1 = *reinterpret_cast<const float4*>(
                wbase + (size_t)kk*kC + 4);
            const float xv[8] = {xa.x, xa.y, xa.z, xa.w,
                                 xb.x, xb.y, xb.z, xb.w};
            const float wv[8] = {w0.x, w0.y, w0.z, w0.w,
                                 w1.x, w1.y, w1.z, w1.w};
#pragma unroll
            for (int i = 0; i < 8; ++i)
#pragma unroll
                for (int j = 0; j < 8; ++j)
                    acc[i][j] = fmaf(xv[i], wv[j], acc[i][j]);
        }
        if (c < 7) {
            const int nxt = cur ^ 1;
#pragma unroll
            for (int r = 0; r < 8; ++r) {
                xs[nxt][(r*4+0)*STR + tid] = gx[r].x;
                xs[nxt][(r*4+1)*STR + tid] = gx[r].y;
                xs[nxt][(r*4+2)*STR + tid] = gx[r].z;
                xs[nxt][(r*4+3)*STR + tid] = gx[r].w;
            }
        }
    }

    // per-node softmax-argmax: 64 cols spread across 8 tx-lanes x 8 regs
#pragma unroll
    for (int i = 0; i < 8; ++i) {
        float m = acc[i][0];
        int   ci = tx*8;
#pragma unroll
        for (int j = 1; j < 8; ++j)
            if (acc[i][j] > m) { m = acc[i][j]; ci = tx*8 + j; }
#pragma unroll
        for (int off = 1; off < 8; off <<= 1) {
            const float om = __shfl_xor(m, off);
            const int   oc = __shfl_xor(ci, off);
            if (om > m || (om == m && oc < ci)) { m = om; ci = oc; }
        }
        float s = 0.f;
#pragma unroll
        for (int j = 0; j < 8; ++j) s += expf(acc[i][j] - m);
#pragma unroll
        for (int off = 1; off < 8; off <<= 1) s += __shfl_xor(s, off);
        if (tx == 0) {
            const float p = 1.0f / s;
            const int n = nbase + ty*8 + i;
            carr[n] = ci;
            varr[n] = (1.0f - p) + p;   // straight-through forward value
        }
    }
}

// ------------------------------------- K1b: deterministic stable counting sort
__global__ __launch_bounds__(1024) void k_sort(
    const int* __restrict__ carr, int* __restrict__ perm,
    int* __restrict__ startc)
{
    __shared__ int hist[16][64];
    __shared__ int startS[65];
    const int g = blockIdx.x;
    const int tid = threadIdx.x;
    const int w = tid >> 6, lane = tid & 63;
    const int c = carr[g*kNPG + tid];
    hist[tid >> 6][tid & 63] = 0;
    __syncthreads();
    unsigned long long mm = ~0ull;
#pragma unroll
    for (int b = 0; b < 6; ++b) {
        const unsigned long long bal = __ballot((c >> b) & 1);
        mm &= ((c >> b) & 1) ? bal : ~bal;
    }
    const unsigned long long ltmask =
        (lane == 0) ? 0ull : (~0ull >> (64 - lane));
    const int rank_in_wave = __popcll(mm & ltmask);
    const int leader = __ffsll((unsigned long long)mm) - 1;
    if (lane == leader) hist[w][c] = __popcll(mm);
    __syncthreads();
    if (w == 0) {
        int tot = 0;
#pragma unroll
        for (int i = 0; i < 16; ++i) tot += hist[i][lane];
        int pre = tot;
#pragma unroll
        for (int off = 1; off < 64; off <<= 1) {
            const int t = __shfl_up(pre, off);
            if (lane >= off) pre += t;
        }
        startS[lane + 1] = pre;
        if (lane == 0) startS[0] = 0;
    }
    __syncthreads();
    int before = startS[c];
    for (int i = 0; i < w; ++i) before += hist[i][c];
    perm[g*kNPG + before + rank_in_wave] = g*kNPG + tid;
    if (tid < 65) startc[g*65 + tid] = startS[tid];
}

// ------------------------------------- K2: out = S^T x (+ vs2) — atomic-FREE
__global__ __launch_bounds__(1024) void k_pool_x(
    const float* __restrict__ x, const int* __restrict__ perm,
    const int* __restrict__ startc, const float* __restrict__ varr,
    float* __restrict__ out, float* __restrict__ vs2)
{
    const int tid  = threadIdx.x;
    const int g    = blockIdx.x >> 3;
    const int fh   = blockIdx.x & 7;
    const int w    = tid >> 6;
    const int lane = tid & 63;
    const int q    = lane & 7;      // feat quad (float4)
    const int sub  = lane >> 3;     // node slot 0..7
    const int fbase = fh*32 + q*4;
#pragma unroll
    for (int cc = 0; cc < 4; ++cc) {
        const int c = w*4 + cc;
        const int s = startc[g*65 + c];
        const int e = startc[g*65 + c + 1];
        float ax = 0.f, ay = 0.f, az = 0.f, aw = 0.f, v2 = 0.f;
        for (int base = s + sub; base < e; base += 8) {
            const int n = perm[(size_t)g*kNPG + base];
            const float v = varr[n];
            const float4 xv = *reinterpret_cast<const float4*>(
                x + (size_t)n*kF + fbase);
            ax = fmaf(v, xv.x, ax); ay = fmaf(v, xv.y, ay);
            az = fmaf(v, xv.z, az); aw = fmaf(v, xv.w, aw);
            v2 = fmaf(v, v, v2);
        }
#pragma unroll
        for (int off = 8; off < 64; off <<= 1) {
            ax += __shfl_xor(ax, off); ay += __shfl_xor(ay, off);
            az += __shfl_xor(az, off); aw += __shfl_xor(aw, off);
            v2 += __shfl_xor(v2, off);
        }
        if (sub == 0) {
            const float4 o = {ax, ay, az, aw};
            *reinterpret_cast<float4*>(
                out + OFF_OUT + (size_t)(g*kC + c)*kF + fbase) = o;
        }
        if (fh == 0 && lane == 0) vs2[g*kC + c] = v2;
    }
}

// ------------------------------------- K4: adjacency partials (+ a2 partial)
__global__ __launch_bounds__(1024) void k_adj(
    const int* __restrict__ ei, const float* __restrict__ ew,
    const int* __restrict__ carr, const float* __restrict__ varr,
    float* __restrict__ padj, float* __restrict__ a2p)
{
    __shared__ float adj[kC*kC];   // 16 KB
    __shared__ float vls[kNPG];    // 4 KB
    __shared__ int   cls[kNPG];    // 4 KB
    __shared__ float wred[16];
    const int tid = threadIdx.x;
    const int bid = blockIdx.x;             // 256 blocks = 64 graphs x 4
    const int g   = bid >> 2;
    for (int i = tid; i < kC*kC; i += 1024) adj[i] = 0.f;
    vls[tid] = varr[g*kNPG + tid];
    cls[tid] = carr[g*kNPG + tid];
    __syncthreads();
    const int e0 = bid * 8192;
    float a2l = 0.f;
#pragma unroll
    for (int it = 0; it < 8; ++it) {
        const int e  = e0 + it*1024 + tid;
        const int sn = ei[e]      & (kNPG - 1);
        const int dn = ei[kE + e] & (kNPG - 1);
        const float wv = ew[e];
        a2l += wv * wv;
        atomicAdd(&adj[cls[sn]*kC + cls[dn]], wv * vls[sn] * vls[dn]);
    }
    __syncthreads();
#pragma unroll
    for (int r = 0; r < 4; ++r) {
        const int lin = r*1024 + tid;
        padj[(size_t)bid*4096 + lin] = adj[lin];
    }
#pragma unroll
    for (int off = 32; off > 0; off >>= 1) a2l += __shfl_down(a2l, off);
    if ((tid & 63) == 0) wred[tid >> 6] = a2l;
    __syncthreads();
    if (tid == 0) {
        float s = 0.f;
#pragma unroll
        for (int wv = 0; wv < 16; ++wv) s += wred[wv];
        a2p[bid] = s;
    }
}

// ------------------------------------- K5: merge adjacency partials
__global__ __launch_bounds__(256) void k_adj_merge(
    const float* __restrict__ padj, float* __restrict__ out)
{
    const int id = blockIdx.x*256 + threadIdx.x;   // < 262144
    const int g = id >> 12, idx = id & 4095;
    float s = 0.f;
#pragma unroll
    for (int sp = 0; sp < 4; ++sp) s += padj[(size_t)(g*4 + sp)*4096 + idx];
    out[OFF_ADJ + id] = s;
}

// ------------------------------------- K6: link_loss scalar
__global__ __launch_bounds__(256) void k_final(
    const float* __restrict__ vs2, const float* __restrict__ a2p,
    float* __restrict__ out)
{
    const int tid = threadIdx.x;
    float p2l = 0.f, apl = 0.f;
#pragma unroll
    for (int r = 0; r < 16; ++r) {
        const int k = r*256 + tid;
        const float t = vs2[k];
        p2l += t*t;
        const int g = k >> 6, cc = k & 63;
        apl += out[OFF_ADJ + (size_t)g*4096 + cc*65];   // diagonal entries
    }
    float a2l = a2p[tid];
#pragma unroll
    for (int off = 32; off > 0; off >>= 1) {
        p2l += __shfl_down(p2l, off);
        apl += __shfl_down(apl, off);
        a2l += __shfl_down(a2l, off);
    }
    __shared__ float red[3][4];
    if ((tid & 63) == 0) {
        red[0][tid>>6] = p2l; red[1][tid>>6] = apl; red[2][tid>>6] = a2l;
    }
    __syncthreads();
    if (tid == 0) {
        const float p2 = red[0][0]+red[0][1]+red[0][2]+red[0][3];
        const float ap = red[1][0]+red[1][1]+red[1][2]+red[1][3];
        const float a2 = red[2][0]+red[2][1]+red[2][2]+red[2][3];
        const float val = a2 - 2.0f*ap + p2;
        out[OFF_LL] = sqrtf(fmaxf(val, 0.f)) / (float)kE;
        out[OFF_Z]  = 0.0f;
    }
}

// ----------------------------------------------------------------- launch
extern "C" void kernel_launch(void* const* d_in, const int* in_sizes, int n_in,
                              void* d_out, int out_size, void* d_ws, size_t ws_size,
                              hipStream_t stream)
{
    const float* x  = (const float*)d_in[0];
    const int*   ei = (const int*)d_in[1];
    const float* ew = (const float*)d_in[2];
    const float* Wm = (const float*)d_in[5];
    const float* bv = (const float*)d_in[6];
    float* out = (float*)d_out;
    char*  ws  = (char*)d_ws;
    int*   carr  = (int*)(ws + WS_C);
    float* varr  = (float*)(ws + WS_V);
    float* vs2   = (float*)(ws + WS_VS2);
    float* a2p   = (float*)(ws + WS_A2);
    int*   perm  = (int*)(ws + WS_PERM);
    int*   strt  = (int*)(ws + WS_STRT);
    float* padj  = (float*)(ws + WS_PADJ);

    k_const    <<<2065, 256, 0, stream>>>(out);
    k_logits   <<<1024,  64, 0, stream>>>(x, Wm, bv, carr, varr);
    k_sort     <<<64,  1024, 0, stream>>>(carr, perm, strt);
    k_pool_x   <<<512, 1024, 0, stream>>>(x, perm, strt, varr, out, vs2);
    k_adj      <<<256, 1024, 0, stream>>>(ei, ew, carr, varr, padj, a2p);
    k_adj_merge<<<1024, 256, 0, stream>>>(padj, out);
    k_final    <<<1,    256, 0, stream>>>(vs2, a2p, out);
}

// Round 8
// 83.466 us; speedup vs baseline: 1.8602x; 1.8602x over previous
//
#include <hip/hip_runtime.h>
#include <cstdint>
#include <cstddef>

namespace {
constexpr int kN    = 65536;     // nodes
constexpr int kF    = 256;       // feats
constexpr int kC    = 64;        // pools per graph
constexpr int kNPG  = 1024;      // nodes per graph
constexpr int kB    = 64;        // graphs
constexpr int kE    = 2097152;   // edges
constexpr int kK    = kB * kC;   // 4096 global clusters

// d_out offsets (in floats)
constexpr size_t OFF_OUT  = 0;                           // [4096,256]
constexpr size_t OFF_EIDX = (size_t)kK * kF;             // 1048576  [2,262144]
constexpr size_t OFF_ADJ  = OFF_EIDX + 2ull*kB*kC*kC;    // 1572864  [262144]
constexpr size_t OFF_LL   = OFF_ADJ + (size_t)kB*kC*kC;  // 1835008
constexpr size_t OFF_Z    = OFF_LL + 1;                  // 1835009
constexpr size_t OFF_BOUT = OFF_Z + 1;                   // 1835010  [4096]
constexpr size_t OFF_BPTR = OFF_BOUT + kK;               // 1839106  [65]

// ws offsets (bytes). PERM/START overlap PADJ (stream-disjoint lifetimes).
constexpr size_t WS_C    = 0;        // int[65536]
constexpr size_t WS_V    = 262144;   // float[65536]
constexpr size_t WS_VS2  = 524288;   // float[4096]
constexpr size_t WS_A2   = 540672;   // float[256]
constexpr size_t WS_PERM = 544768;   // int[65536]   (dead after k_pool_x)
constexpr size_t WS_STRT = 806912;   // int[64*65]   (dead after k_pool_x)
constexpr size_t WS_PADJ = 544768;   // float[256*4096] = 4 MiB (k_adj onward)
} // namespace

// ---------------------------------------------------------------- constants
__global__ __launch_bounds__(256) void k_const(float* __restrict__ out)
{
    const int i = blockIdx.x * 256 + threadIdx.x;
    constexpr int E2 = 2 * kB * kC * kC;      // 524288
    if (i < E2) {
        const int half = i >= kB*kC*kC;
        const int idx  = half ? i - kB*kC*kC : i;
        const int bb = idx >> 12, rem = idx & 4095;
        const int val = half ? bb*kC + (rem & 63) : bb*kC + (rem >> 6);
        out[OFF_EIDX + i] = (float)val;
    } else if (i < E2 + kK) {
        const int j = i - E2;
        out[OFF_BOUT + j] = (float)(j >> 6);
    } else if (i < E2 + kK + kB + 1) {
        const int j = i - (E2 + kK);
        out[OFF_BPTR + j] = (float)(j * kC);
    }
}

// ------------------------------------------------- K1: logits -> c, v
// GEMM M=65536 N=64 K=256. 512-thread blocks (8 waves), BM=128 nodes.
// Wave w owns cols w*8..w*8+7 (wave-uniform via readfirstlane -> W and bias
// come through the SCALAR path: s_load + SGPR operand in v_fma; zero
// vector-LDS, zero per-kk vector loads). Lane owns 2 nodes -> 2x8 tile.
// Grid 512 -> 2 blocks/CU -> 16 waves/CU = 4/SIMD (latency hiding).
// Per kk per wave: 1 ds_read_b64 (x-frag; data-floor cost) + 16 FMA.
// x staged [k][node] stride 130: transpose writes & frag reads 2-way (free).
__global__ __launch_bounds__(512) void k_logits(
    const float* __restrict__ x, const float* __restrict__ Wm,
    const float* __restrict__ bv, int* __restrict__ carr,
    float* __restrict__ varr)
{
    constexpr int KC = 32, STR = 130;
    __shared__ float xs[2][KC * STR];   // 33280 B
    const int tid  = threadIdx.x;       // 0..511
    const int lane = tid & 63;
    const int wgu  = __builtin_amdgcn_readfirstlane(tid >> 6);  // SGPR, 0..7
    const int nbase = blockIdx.x * 128;
    const float* __restrict__ wcol = Wm + wgu * 8;

    // staging slots: 1024 float4 slots (128 nodes x 8 k-quads), 2 per thread
    const int i0 = tid * 2,      n0s = i0 >> 3, q0 = i0 & 7;
    const int i1 = tid * 2 + 1,  n1s = i1 >> 3, q1 = i1 & 7;
    const float* __restrict__ xr0 = x + (size_t)(nbase + n0s) * kF + q0 * 4;
    const float* __restrict__ xr1 = x + (size_t)(nbase + n1s) * kF + q1 * 4;

    float acc[2][8];
#pragma unroll
    for (int j = 0; j < 8; ++j) {
        const float b = bv[wgu*8 + j];       // uniform -> s_load
        acc[0][j] = b; acc[1][j] = b;
    }

    // prologue: stage chunk 0
    {
        const float4 g0 = *reinterpret_cast<const float4*>(xr0);
        const float4 g1 = *reinterpret_cast<const float4*>(xr1);
        xs[0][(q0*4+0)*STR + n0s] = g0.x; xs[0][(q0*4+1)*STR + n0s] = g0.y;
        xs[0][(q0*4+2)*STR + n0s] = g0.z; xs[0][(q0*4+3)*STR + n0s] = g0.w;
        xs[0][(q1*4+0)*STR + n1s] = g1.x; xs[0][(q1*4+1)*STR + n1s] = g1.y;
        xs[0][(q1*4+2)*STR + n1s] = g1.z; xs[0][(q1*4+3)*STR + n1s] = g1.w;
    }

#pragma unroll 1
    for (int c = 0; c < 8; ++c) {
        const int cur = c & 1;
        float4 g0, g1;
        if (c < 7) {
            g0 = *reinterpret_cast<const float4*>(xr0 + (c+1)*KC);
            g1 = *reinterpret_cast<const float4*>(xr1 + (c+1)*KC);
        }
        __syncthreads();   // staged writes for chunk c visible
        const float* __restrict__ wrow = wcol + (size_t)c * KC * kC;
#pragma unroll 8
        for (int kk = 0; kk < KC; ++kk) {
            const float2 xv = *reinterpret_cast<const float2*>(
                &xs[cur][kk*STR + lane*2]);
            const float4 w0 = *reinterpret_cast<const float4*>(
                wrow + (size_t)kk*kC);          // uniform -> s_load
            const float4 w1 = *reinterpret_cast<const float4*>(
                wrow + (size_t)kk*kC + 4);
            const float wv[8] = {w0.x, w0.y, w0.z, w0.w,
                                 w1.x, w1.y, w1.z, w1.w};
#pragma unroll
            for (int j = 0; j < 8; ++j) {
                acc[0][j] = fmaf(xv.x, wv[j], acc[0][j]);
                acc[1][j] = fmaf(xv.y, wv[j], acc[1][j]);
            }
        }
        if (c < 7) {
            __syncthreads();   // all waves done computing chunk c
            const int nxt = cur ^ 1;
            xs[nxt][(q0*4+0)*STR + n0s] = g0.x;
            xs[nxt][(q0*4+1)*STR + n0s] = g0.y;
            xs[nxt][(q0*4+2)*STR + n0s] = g0.z;
            xs[nxt][(q0*4+3)*STR + n0s] = g0.w;
            xs[nxt][(q1*4+0)*STR + n1s] = g1.x;
            xs[nxt][(q1*4+1)*STR + n1s] = g1.y;
            xs[nxt][(q1*4+2)*STR + n1s] = g1.z;
            xs[nxt][(q1*4+3)*STR + n1s] = g1.w;
        }
    }

    // epilogue: per-wave partial (max, argmax, sumexp) -> LDS -> combine.
    float* ep_m = &xs[0][0];            // [8][128]
    float* ep_s = ep_m + 1024;          // [8][128]
    int*   ep_i = (int*)(ep_s + 1024);  // [8][128]
    __syncthreads();
#pragma unroll
    for (int u = 0; u < 2; ++u) {
        float m = acc[u][0]; int ji = 0;
#pragma unroll
        for (int j = 1; j < 8; ++j)
            if (acc[u][j] > m) { m = acc[u][j]; ji = j; }
        float s = 0.f;
#pragma unroll
        for (int j = 0; j < 8; ++j) s += expf(acc[u][j] - m);
        const int nl = lane*2 + u;
        ep_m[wgu*128 + nl] = m;
        ep_s[wgu*128 + nl] = s;
        ep_i[wgu*128 + nl] = wgu*8 + ji;
    }
    __syncthreads();
    if (tid < 128) {
        float M = ep_m[tid]; int C = ep_i[tid];
#pragma unroll
        for (int w = 1; w < 8; ++w) {
            const float mw = ep_m[w*128 + tid];
            if (mw > M) { M = mw; C = ep_i[w*128 + tid]; }
        }
        float tot = 0.f;
#pragma unroll
        for (int w = 0; w < 8; ++w)
            tot += ep_s[w*128 + tid] * expf(ep_m[w*128 + tid] - M);
        const float p = 1.0f / tot;
        carr[nbase + tid] = C;
        varr[nbase + tid] = (1.0f - p) + p;   // straight-through forward
    }
}

// ------------------------------------- K1b: deterministic stable counting sort
__global__ __launch_bounds__(1024) void k_sort(
    const int* __restrict__ carr, int* __restrict__ perm,
    int* __restrict__ startc)
{
    __shared__ int hist[16][64];
    __shared__ int startS[65];
    const int g = blockIdx.x;
    const int tid = threadIdx.x;
    const int w = tid >> 6, lane = tid & 63;
    const int c = carr[g*kNPG + tid];
    hist[tid >> 6][tid & 63] = 0;
    __syncthreads();
    unsigned long long mm = ~0ull;
#pragma unroll
    for (int b = 0; b < 6; ++b) {
        const unsigned long long bal = __ballot((c >> b) & 1);
        mm &= ((c >> b) & 1) ? bal : ~bal;
    }
    const unsigned long long ltmask =
        (lane == 0) ? 0ull : (~0ull >> (64 - lane));
    const int rank_in_wave = __popcll(mm & ltmask);
    const int leader = __ffsll((unsigned long long)mm) - 1;
    if (lane == leader) hist[w][c] = __popcll(mm);
    __syncthreads();
    if (w == 0) {
        int tot = 0;
#pragma unroll
        for (int i = 0; i < 16; ++i) tot += hist[i][lane];
        int pre = tot;
#pragma unroll
        for (int off = 1; off < 64; off <<= 1) {
            const int t = __shfl_up(pre, off);
            if (lane >= off) pre += t;
        }
        startS[lane + 1] = pre;
        if (lane == 0) startS[0] = 0;
    }
    __syncthreads();
    int before = startS[c];
    for (int i = 0; i < w; ++i) before += hist[i][c];
    perm[g*kNPG + before + rank_in_wave] = g*kNPG + tid;
    if (tid < 65) startc[g*65 + tid] = startS[tid];
}

// ------------------------------------- K2: out = S^T x (+ vs2) — atomic-FREE
__global__ __launch_bounds__(1024) void k_pool_x(
    const float* __restrict__ x, const int* __restrict__ perm,
    const int* __restrict__ startc, const float* __restrict__ varr,
    float* __restrict__ out, float* __restrict__ vs2)
{
    const int tid  = threadIdx.x;
    const int g    = blockIdx.x >> 3;
    const int fh   = blockIdx.x & 7;
    const int w    = tid >> 6;
    const int lane = tid & 63;
    const int q    = lane & 7;      // feat quad (float4)
    const int sub  = lane >> 3;     // node slot 0..7
    const int fbase = fh*32 + q*4;
#pragma unroll
    for (int cc = 0; cc < 4; ++cc) {
        const int c = w*4 + cc;
        const int s = startc[g*65 + c];
        const int e = startc[g*65 + c + 1];
        float ax = 0.f, ay = 0.f, az = 0.f, aw = 0.f, v2 = 0.f;
        for (int base = s + sub; base < e; base += 8) {
            const int n = perm[(size_t)g*kNPG + base];
            const float v = varr[n];
            const float4 xv = *reinterpret_cast<const float4*>(
                x + (size_t)n*kF + fbase);
            ax = fmaf(v, xv.x, ax); ay = fmaf(v, xv.y, ay);
            az = fmaf(v, xv.z, az); aw = fmaf(v, xv.w, aw);
            v2 = fmaf(v, v, v2);
        }
#pragma unroll
        for (int off = 8; off < 64; off <<= 1) {
            ax += __shfl_xor(ax, off); ay += __shfl_xor(ay, off);
            az += __shfl_xor(az, off); aw += __shfl_xor(aw, off);
            v2 += __shfl_xor(v2, off);
        }
        if (sub == 0) {
            const float4 o = {ax, ay, az, aw};
            *reinterpret_cast<float4*>(
                out + OFF_OUT + (size_t)(g*kC + c)*kF + fbase) = o;
        }
        if (fh == 0 && lane == 0) vs2[g*kC + c] = v2;
    }
}

// ------------------------------------- K4: adjacency partials (+ a2 partial)
__global__ __launch_bounds__(1024) void k_adj(
    const int* __restrict__ ei, const float* __restrict__ ew,
    const int* __restrict__ carr, const float* __restrict__ varr,
    float* __restrict__ padj, float* __restrict__ a2p)
{
    __shared__ float adj[kC*kC];   // 16 KB
    __shared__ float vls[kNPG];    // 4 KB
    __shared__ int   cls[kNPG];    // 4 KB
    __shared__ float wred[16];
    const int tid = threadIdx.x;
    const int bid = blockIdx.x;             // 256 blocks = 64 graphs x 4
    const int g   = bid >> 2;
    for (int i = tid; i < kC*kC; i += 1024) adj[i] = 0.f;
    vls[tid] = varr[g*kNPG + tid];
    cls[tid] = carr[g*kNPG + tid];
    __syncthreads();
    const int e0 = bid * 8192;
    float a2l = 0.f;
#pragma unroll
    for (int it = 0; it < 8; ++it) {
        const int e  = e0 + it*1024 + tid;
        const int sn = ei[e]      & (kNPG - 1);
        const int dn = ei[kE + e] & (kNPG - 1);
        const float wv = ew[e];
        a2l += wv * wv;
        atomicAdd(&adj[cls[sn]*kC + cls[dn]], wv * vls[sn] * vls[dn]);
    }
    __syncthreads();
#pragma unroll
    for (int r = 0; r < 4; ++r) {
        const int lin = r*1024 + tid;
        padj[(size_t)bid*4096 + lin] = adj[lin];
    }
#pragma unroll
    for (int off = 32; off > 0; off >>= 1) a2l += __shfl_down(a2l, off);
    if ((tid & 63) == 0) wred[tid >> 6] = a2l;
    __syncthreads();
    if (tid == 0) {
        float s = 0.f;
#pragma unroll
        for (int wv = 0; wv < 16; ++wv) s += wred[wv];
        a2p[bid] = s;
    }
}

// ------------------------------------- K5: merge adjacency partials
__global__ __launch_bounds__(256) void k_adj_merge(
    const float* __restrict__ padj, float* __restrict__ out)
{
    const int id = blockIdx.x*256 + threadIdx.x;   // < 262144
    const int g = id >> 12, idx = id & 4095;
    float s = 0.f;
#pragma unroll
    for (int sp = 0; sp < 4; ++sp) s += padj[(size_t)(g*4 + sp)*4096 + idx];
    out[OFF_ADJ + id] = s;
}

// ------------------------------------- K6: link_loss scalar
__global__ __launch_bounds__(256) void k_final(
    const float* __restrict__ vs2, const float* __restrict__ a2p,
    float* __restrict__ out)
{
    const int tid = threadIdx.x;
    float p2l = 0.f, apl = 0.f;
#pragma unroll
    for (int r = 0; r < 16; ++r) {
        const int k = r*256 + tid;
        const float t = vs2[k];
        p2l += t*t;
        const int g = k >> 6, cc = k & 63;
        apl += out[OFF_ADJ + (size_t)g*4096 + cc*65];   // diagonal entries
    }
    float a2l = a2p[tid];
#pragma unroll
    for (int off = 32; off > 0; off >>= 1) {
        p2l += __shfl_down(p2l, off);
        apl += __shfl_down(apl, off);
        a2l += __shfl_down(a2l, off);
    }
    __shared__ float red[3][4];
    if ((tid & 63) == 0) {
        red[0][tid>>6] = p2l; red[1][tid>>6] = apl; red[2][tid>>6] = a2l;
    }
    __syncthreads();
    if (tid == 0) {
        const float p2 = red[0][0]+red[0][1]+red[0][2]+red[0][3];
        const float ap = red[1][0]+red[1][1]+red[1][2]+red[1][3];
        const float a2 = red[2][0]+red[2][1]+red[2][2]+red[2][3];
        const float val = a2 - 2.0f*ap + p2;
        out[OFF_LL] = sqrtf(fmaxf(val, 0.f)) / (float)kE;
        out[OFF_Z]  = 0.0f;
    }
}

// ----------------------------------------------------------------- launch
extern "C" void kernel_launch(void* const* d_in, const int* in_sizes, int n_in,
                              void* d_out, int out_size, void* d_ws, size_t ws_size,
                              hipStream_t stream)
{
    const float* x  = (const float*)d_in[0];
    const int*   ei = (const int*)d_in[1];
    const float* ew = (const float*)d_in[2];
    const float* Wm = (const float*)d_in[5];
    const float* bv = (const float*)d_in[6];
    float* out = (float*)d_out;
    char*  ws  = (char*)d_ws;
    int*   carr  = (int*)(ws + WS_C);
    float* varr  = (float*)(ws + WS_V);
    float* vs2   = (float*)(ws + WS_VS2);
    float* a2p   = (float*)(ws + WS_A2);
    int*   perm  = (int*)(ws + WS_PERM);
    int*   strt  = (int*)(ws + WS_STRT);
    float* padj  = (float*)(ws + WS_PADJ);

    k_const    <<<2065, 256, 0, stream>>>(out);
    k_logits   <<<512,  512, 0, stream>>>(x, Wm, bv, carr, varr);
    k_sort     <<<64,  1024, 0, stream>>>(carr, perm, strt);
    k_pool_x   <<<512, 1024, 0, stream>>>(x, perm, strt, varr, out, vs2);
    k_adj      <<<256, 1024, 0, stream>>>(ei, ew, carr, varr, padj, a2p);
    k_adj_merge<<<1024, 256, 0, stream>>>(padj, out);
    k_final    <<<1,    256, 0, stream>>>(vs2, a2p, out);
}